// Round 2
// baseline (95.612 us; speedup 1.0000x reference)
//
#include <hip/hip_runtime.h>
#include <hip/hip_bf16.h>

#define BB 2
#define TT 15
#define NN 2048
#define TO 8
#define MM 64
#define KH 32
#define DIMD 512
#define R2 0.49f

// ---------------- FPS: one block per (b,f) frame; orig frame t = 2f ----------------
__global__ __launch_bounds__(256) void fps_kernel(const float* __restrict__ input,
                                                  float* __restrict__ anchor_xyz) {
    __shared__ float xs[NN], ys[NN], zs[NN];
    __shared__ float swv[4];
    __shared__ int   swi[4];
    int blk = blockIdx.x;            // 0..15 = b*8+f
    int b = blk >> 3, f = blk & 7;
    const float* src = input + ((size_t)(b * TT + 2 * f)) * NN * 3;
    int tid = threadIdx.x;
    for (int p = tid; p < NN; p += 256) {
        xs[p] = src[p * 3 + 0];
        ys[p] = src[p * 3 + 1];
        zs[p] = src[p * 3 + 2];
    }
    __syncthreads();

    float mind[8];
#pragma unroll
    for (int j = 0; j < 8; ++j) mind[j] = 1e10f;
    int last = 0;
    float* out = anchor_xyz + (size_t)blk * MM * 3;
    if (tid == 0) { out[0] = xs[0]; out[1] = ys[0]; out[2] = zs[0]; }

    for (int it = 1; it < MM; ++it) {
        float lx = xs[last], ly = ys[last], lz = zs[last];
        float bv = -1.0f; int bi = NN;
#pragma unroll
        for (int j = 0; j < 8; ++j) {
            int p = tid + 256 * j;
            float dx = xs[p] - lx, dy = ys[p] - ly, dz = zs[p] - lz;
            // no-FMA, fixed order: ((dx*dx + dy*dy) + dz*dz) to match numpy bitwise
            float d = __fadd_rn(__fadd_rn(__fmul_rn(dx, dx), __fmul_rn(dy, dy)),
                                __fmul_rn(dz, dz));
            float mv = fminf(mind[j], d);
            mind[j] = mv;
            if (mv > bv) { bv = mv; bi = p; }           // p strictly increasing per thread
        }
        // wave butterfly argmax with first-index tie-break
#pragma unroll
        for (int off = 32; off >= 1; off >>= 1) {
            float ov = __shfl_xor(bv, off);
            int   oi = __shfl_xor(bi, off);
            if (ov > bv || (ov == bv && oi < bi)) { bv = ov; bi = oi; }
        }
        int w = tid >> 6;
        if ((tid & 63) == 0) { swv[w] = bv; swi[w] = bi; }
        __syncthreads();
        bv = swv[0]; bi = swi[0];
#pragma unroll
        for (int ww = 1; ww < 4; ++ww) {
            float ov = swv[ww]; int oi = swi[ww];
            if (ov > bv || (ov == bv && oi < bi)) { bv = ov; bi = oi; }
        }
        last = bi;
        if (tid == 0) { out[it * 3 + 0] = xs[last]; out[it * 3 + 1] = ys[last]; out[it * 3 + 2] = zs[last]; }
        __syncthreads();   // WAR on swv/swi before next iteration
    }
}

// ---------------- Encode: one block per anchor (b,f,m); 256 threads = 2 dims each ----------------
__global__ __launch_bounds__(256) void encode_kernel(const float* __restrict__ input,
                                                     const float* __restrict__ W_d,
                                                     const float* __restrict__ W_f,
                                                     const float* __restrict__ W_pos,
                                                     const float* __restrict__ b_pos,
                                                     const float* __restrict__ anchor_xyz,
                                                     float* __restrict__ outp) {
    __shared__ float hx[KH], hy[KH], hz[KH];
    __shared__ int swtot[4];
    int bid = blockIdx.x;                 // b*512 + f*64 + m
    int b = bid >> 9;
    int rem = bid & 511;
    int f = rem >> 6;
    int m = rem & 63;
    int tid = threadIdx.x, lane = tid & 63, w = tid >> 6;

    const float* anc = anchor_xyz + (size_t)(((b << 3) + f) * MM + m) * 3;
    float ax = anc[0], ay = anc[1], az = anc[2];

    int d0 = tid, d1 = tid + 256;
    float4 wd0 = ((const float4*)W_d)[d0];
    float4 wd1 = ((const float4*)W_d)[d1];
    float  wf0 = W_f[d0], wf1 = W_f[d1];
    float p0 = -INFINITY, p1 = -INFINITY;

    for (int dt = -1; dt <= 1; ++dt) {
        int frame = 2 * f + dt;
        frame = frame < 0 ? 0 : (frame > 14 ? 14 : frame);
        const float* src = input + ((size_t)(b * TT + frame)) * NN * 3;

        // thread t owns consecutive points [8t, 8t+8)
        float px[8], py[8], pz[8];
        const float4* s4 = (const float4*)(src + tid * 24);
        float4 v0 = s4[0], v1 = s4[1], v2 = s4[2], v3 = s4[3], v4 = s4[4], v5 = s4[5];
        px[0] = v0.x; py[0] = v0.y; pz[0] = v0.z;
        px[1] = v0.w; py[1] = v1.x; pz[1] = v1.y;
        px[2] = v1.z; py[2] = v1.w; pz[2] = v2.x;
        px[3] = v2.y; py[3] = v2.z; pz[3] = v2.w;
        px[4] = v3.x; py[4] = v3.y; pz[4] = v3.z;
        px[5] = v3.w; py[5] = v4.x; pz[5] = v4.y;
        px[6] = v4.z; py[6] = v4.w; pz[6] = v5.x;
        px[7] = v5.y; py[7] = v5.z; pz[7] = v5.w;

        unsigned hit = 0; int cnt = 0;
#pragma unroll
        for (int j = 0; j < 8; ++j) {
            float dx = ax - px[j], dy = ay - py[j], dz = az - pz[j];
            float d2 = __fadd_rn(__fadd_rn(__fmul_rn(dx, dx), __fmul_rn(dy, dy)),
                                 __fmul_rn(dz, dz));
            if (d2 < R2) { hit |= 1u << j; cnt++; }
        }
        // wave inclusive scan of cnt
        int s = cnt;
#pragma unroll
        for (int off = 1; off < 64; off <<= 1) {
            int o = __shfl_up(s, off);
            if (lane >= off) s += o;
        }
        if (lane == 63) swtot[w] = s;
        __syncthreads();
        int wavebase = 0, total = 0;
#pragma unroll
        for (int ww = 0; ww < 4; ++ww) {
            int t2 = swtot[ww];
            total += t2;
            if (ww < w) wavebase += t2;
        }
        int r = wavebase + s - cnt;   // exclusive global rank of this thread's first hit
#pragma unroll
        for (int j = 0; j < 8; ++j) {
            if (hit & (1u << j)) {
                if (r < KH) { hx[r] = px[j]; hy[r] = py[j]; hz[r] = pz[j]; }
                r++;
            }
        }
        if (total == 0 && tid == 0) { hx[0] = px[0]; hy[0] = py[0]; hz[0] = pz[0]; }
        __syncthreads();

        int nh = (total == 0) ? 1 : (total < KH ? total : KH);
        float dtf = (float)dt;
        for (int k = 0; k < nh; ++k) {
            float gx = hx[k], gy = hy[k], gz = hz[k];
            float dx = gx - ax, dy = gy - ay, dz = gz - az;
            float v0d = dx * wd0.x + dy * wd0.y + dz * wd0.z + dtf * wd0.w + gz * wf0;
            float v1d = dx * wd1.x + dy * wd1.y + dz * wd1.z + dtf * wd1.w + gz * wf1;
            p0 = fmaxf(p0, v0d);
            p1 = fmaxf(p1, v1d);
        }
        __syncthreads();   // WAR on hx/hy/hz/swtot before next dt
    }

    // epilogue: positional linear + bias + relu, float32 store
    float4 wp0 = ((const float4*)W_pos)[d0];
    float4 wp1 = ((const float4*)W_pos)[d1];
    float tv = (float)(f + 1);
    float pos0 = ax * wp0.x + ay * wp0.y + az * wp0.z + tv * wp0.w + b_pos[d0];
    float pos1 = ax * wp1.x + ay * wp1.y + az * wp1.z + tv * wp1.w + b_pos[d1];
    float o0 = fmaxf(pos0 + p0, 0.0f);
    float o1 = fmaxf(pos1 + p1, 0.0f);
    size_t row = ((size_t)b * (TO * MM) + f * MM + m) * DIMD;
    outp[row + d0] = o0;
    outp[row + d1] = o1;
}

extern "C" void kernel_launch(void* const* d_in, const int* in_sizes, int n_in,
                              void* d_out, int out_size, void* d_ws, size_t ws_size,
                              hipStream_t stream) {
    const float* input = (const float*)d_in[0];
    const float* W_d   = (const float*)d_in[1];
    const float* W_f   = (const float*)d_in[2];
    const float* W_pos = (const float*)d_in[3];
    const float* b_pos = (const float*)d_in[4];
    float* anchor = (float*)d_ws;   // 16*64*3 floats = 12 KB

    fps_kernel<<<16, 256, 0, stream>>>(input, anchor);
    encode_kernel<<<1024, 256, 0, stream>>>(input, W_d, W_f, W_pos, b_pos, anchor,
                                            (float*)d_out);
}